// Round 1
// baseline (501.623 us; speedup 1.0000x reference)
//
#include <hip/hip_runtime.h>

#define FEPS 1e-12f

constexpr int NB = 64;           // batch
constexpr int D  = 256;          // channels
constexpr int T  = 4096;         // H*W
constexpr int K  = 64;           // clusters
constexpr int S  = 8;            // t-splits per image (blocks per n)
constexpr int TBLK = T / S;      // 512 pixels per block
constexpr int TC   = 128;        // pixels per chunk
constexpr int NCH  = TBLK / TC;  // 4 chunks
constexpr int DT   = 32;         // d-tile staged in LDS
constexpr int NDT  = D / DT;     // 8 tiles

// Swizzled LDS index for the transposed x tile xsT[t][d] (t:0..127, d:0..31).
// 16B-group swizzle: group g=d>>2 is XORed with (t&7)^((t>>3)&7) so that
//  - staging b128 writes (lane=t, fixed g) spread over 8 bank-groups
//  - GEMM1 b128 reads (t=8*tj+i) get distinct groups per tj  -> conflict-free
__device__ __forceinline__ int xidx(int t, int d) {
    int g = ((d >> 2) ^ t ^ (t >> 3)) & 7;
    return (t << 5) + (g << 2) + (d & 3);
}

// Fused: L2-norm factor + logits GEMM + softmax + aggregation GEMM.
// grid = (S, NB), block = 256.  LDS ~61KB -> 2 blocks/CU.
__global__ __launch_bounds__(256, 2)
void nv_main(const float* __restrict__ x, const float* __restrict__ wT,
             float* __restrict__ vlad, float* __restrict__ suma)
{
    __shared__ float xsT[TC * DT];       // 16 KB, swizzled [t][d]
    __shared__ float wTt[DT][64];        // 8 KB,  w transposed tile [d][k]
    __shared__ float bTt[TC][68];        // 34 KB, b = a*r, [t][k] (+4 pad)
    __shared__ float r_l[TC];
    __shared__ float sq_part[2][TC];
    __shared__ float suma_sh[K];

    const int tid = threadIdx.x;
    const int n   = blockIdx.y;
    const int ki  = tid & 15;            // k-group: k = 4*ki+kk
    const int tj  = tid >> 4;            // GEMM1: t-group; GEMM2: d-group
    const int tl  = tid & 127;           // staging: pixel
    const int dg  = tid >> 7;            // staging: d half

    if (tid < K) suma_sh[tid] = 0.f;

    const float* xn = x + (size_t)n * D * T;

    float vacc[4][16];                   // [kk][tile*2+e] (d = tile*32 + tj*2 + e)
    #pragma unroll
    for (int a = 0; a < 4; ++a)
        #pragma unroll
        for (int b = 0; b < 16; ++b) vacc[a][b] = 0.f;
    float sa[4] = {0.f, 0.f, 0.f, 0.f};  // sum of softmax a (for centroid term)

    for (int c = 0; c < NCH; ++c) {
        const int t0 = blockIdx.x * TBLK + c * TC;
        float sq = 0.f;
        float z[4][8];                   // logits pre-scale: [kk][i], t = tj*8+i
        #pragma unroll
        for (int a = 0; a < 4; ++a)
            #pragma unroll
            for (int i = 0; i < 8; ++i) z[a][i] = 0.f;

        // ---- Phase 1: GEMM1 (z = W * x) streaming d-tiles, sumsq fused ----
        for (int tile = 0; tile < NDT; ++tile) {
            __syncthreads();             // protect xsT/wTt from previous readers
            #pragma unroll
            for (int p = 0; p < 4; ++p) {
                const int di = (p << 3) + (dg << 2);
                const float* src = xn + (size_t)(tile * DT + di) * T + t0 + tl;
                float4 v;
                v.x = src[0];
                v.y = src[T];
                v.z = src[2 * T];
                v.w = src[3 * T];
                sq = fmaf(v.x, v.x, sq); sq = fmaf(v.y, v.y, sq);
                sq = fmaf(v.z, v.z, sq); sq = fmaf(v.w, v.w, sq);
                *reinterpret_cast<float4*>(&xsT[xidx(tl, di)]) = v;
            }
            {   // stage wT tile: 32x64, 8 f32/thread, coalesced global reads
                const int rr = tid >> 3;
                const int cc = (tid & 7) << 3;
                const float* wsrc = wT + (size_t)(tile * DT + rr) * 64 + cc;
                float4 a0 = *reinterpret_cast<const float4*>(wsrc);
                float4 a1 = *reinterpret_cast<const float4*>(wsrc + 4);
                *reinterpret_cast<float4*>(&wTt[rr][cc])     = a0;
                *reinterpret_cast<float4*>(&wTt[rr][cc + 4]) = a1;
            }
            __syncthreads();
            #pragma unroll
            for (int q = 0; q < 8; ++q) {        // 4 d's per q
                float wv[4][4];
                #pragma unroll
                for (int j = 0; j < 4; ++j) {
                    float4 w4 = *reinterpret_cast<const float4*>(&wTt[(q << 2) + j][ki << 2]);
                    wv[j][0] = w4.x; wv[j][1] = w4.y; wv[j][2] = w4.z; wv[j][3] = w4.w;
                }
                #pragma unroll
                for (int i = 0; i < 8; ++i) {
                    float4 x4 = *reinterpret_cast<const float4*>(&xsT[xidx((tj << 3) + i, q << 2)]);
                    float xj[4] = {x4.x, x4.y, x4.z, x4.w};
                    #pragma unroll
                    for (int j = 0; j < 4; ++j) {
                        #pragma unroll
                        for (int kk = 0; kk < 4; ++kk)
                            z[kk][i] = fmaf(wv[j][kk], xj[j], z[kk][i]);
                    }
                }
            }
        }

        // ---- r[t] = 1/max(||x[:,t]||, eps) ----
        __syncthreads();
        sq_part[dg][tl] = sq;
        __syncthreads();
        if (tid < TC) {
            float s = sq_part[0][tid] + sq_part[1][tid];
            r_l[tid] = 1.f / fmaxf(sqrtf(s), FEPS);
        }
        __syncthreads();

        // ---- Phase 2: softmax over k (64 across 16 lanes x 4 regs), b = a*r ----
        #pragma unroll
        for (int i = 0; i < 8; ++i) {
            const int t = (tj << 3) + i;
            const float r = r_l[t];
            float l0 = z[0][i] * r, l1 = z[1][i] * r, l2 = z[2][i] * r, l3 = z[3][i] * r;
            float m = fmaxf(fmaxf(l0, l1), fmaxf(l2, l3));
            #pragma unroll
            for (int msk = 1; msk <= 8; msk <<= 1)
                m = fmaxf(m, __shfl_xor(m, msk));
            float e0 = __expf(l0 - m), e1 = __expf(l1 - m);
            float e2 = __expf(l2 - m), e3 = __expf(l3 - m);
            float s = e0 + e1 + e2 + e3;
            #pragma unroll
            for (int msk = 1; msk <= 8; msk <<= 1)
                s += __shfl_xor(s, msk);
            const float inv = 1.f / s;
            sa[0] = fmaf(e0, inv, sa[0]);
            sa[1] = fmaf(e1, inv, sa[1]);
            sa[2] = fmaf(e2, inv, sa[2]);
            sa[3] = fmaf(e3, inv, sa[3]);
            const float br = inv * r;
            float4 bv;
            bv.x = e0 * br; bv.y = e1 * br; bv.z = e2 * br; bv.w = e3 * br;
            *reinterpret_cast<float4*>(&bTt[t][ki << 2]) = bv;
        }

        // ---- Phase 3: GEMM2  vlad[k][d] += b[k][t] * x[d][t] ----
        #pragma unroll
        for (int tile = 0; tile < NDT; ++tile) {   // full unroll: static vacc idx
            __syncthreads();
            #pragma unroll
            for (int p = 0; p < 4; ++p) {          // re-stage x tile (L2-warm)
                const int di = (p << 3) + (dg << 2);
                const float* src = xn + (size_t)(tile * DT + di) * T + t0 + tl;
                float4 v;
                v.x = src[0]; v.y = src[T]; v.z = src[2 * T]; v.w = src[3 * T];
                *reinterpret_cast<float4*>(&xsT[xidx(tl, di)]) = v;
            }
            __syncthreads();
            #pragma unroll 4
            for (int t = 0; t < TC; ++t) {
                float4 b4 = *reinterpret_cast<const float4*>(&bTt[t][ki << 2]);
                float2 x2 = *reinterpret_cast<const float2*>(&xsT[xidx(t, tj << 1)]);
                vacc[0][(tile << 1)    ] = fmaf(b4.x, x2.x, vacc[0][(tile << 1)    ]);
                vacc[0][(tile << 1) + 1] = fmaf(b4.x, x2.y, vacc[0][(tile << 1) + 1]);
                vacc[1][(tile << 1)    ] = fmaf(b4.y, x2.x, vacc[1][(tile << 1)    ]);
                vacc[1][(tile << 1) + 1] = fmaf(b4.y, x2.y, vacc[1][(tile << 1) + 1]);
                vacc[2][(tile << 1)    ] = fmaf(b4.z, x2.x, vacc[2][(tile << 1)    ]);
                vacc[2][(tile << 1) + 1] = fmaf(b4.z, x2.y, vacc[2][(tile << 1) + 1]);
                vacc[3][(tile << 1)    ] = fmaf(b4.w, x2.x, vacc[3][(tile << 1)    ]);
                vacc[3][(tile << 1) + 1] = fmaf(b4.w, x2.y, vacc[3][(tile << 1) + 1]);
            }
        }
    }

    // ---- flush per-block vlad partials (8 blocks/location) + suma ----
    float* vout = vlad + (size_t)n * K * D;
    #pragma unroll
    for (int kk = 0; kk < 4; ++kk) {
        const int krow = ((ki << 2) + kk) << 8;   // *256
        #pragma unroll
        for (int tile = 0; tile < 8; ++tile) {
            atomicAdd(&vout[krow + tile * 32 + (tj << 1)    ], vacc[kk][(tile << 1)    ]);
            atomicAdd(&vout[krow + tile * 32 + (tj << 1) + 1], vacc[kk][(tile << 1) + 1]);
        }
    }
    #pragma unroll
    for (int kk = 0; kk < 4; ++kk)
        atomicAdd(&suma_sh[(ki << 2) + kk], sa[kk]);
    __syncthreads();
    if (tid < K) atomicAdd(&suma[n * K + tid], suma_sh[tid]);
}

// transpose conv_w (K,D) -> wT (D,K) once
__global__ void nv_prep(const float* __restrict__ w, float* __restrict__ wT) {
    const int idx = blockIdx.x * 256 + threadIdx.x;   // over D*K
    const int d = idx >> 6, k = idx & 63;
    wT[idx] = w[k * 256 + d];
}

// per (n,k): subtract suma*centroid, intra-normalize over d, accum final sumsq
__global__ void nv_finish_row(const float* __restrict__ cent,
                              const float* __restrict__ suma,
                              float* __restrict__ out,
                              float* __restrict__ nsum)
{
    const int bid = blockIdx.x;          // n*64 + k
    const int k = bid & 63;
    const int d = threadIdx.x;
    float v = out[(size_t)bid * 256 + d] - suma[bid] * cent[k * 256 + d];
    float sv = v * v;
    #pragma unroll
    for (int msk = 1; msk < 64; msk <<= 1) sv += __shfl_xor(sv, msk);
    __shared__ float red[4];
    __shared__ float stot;
    if ((d & 63) == 0) red[d >> 6] = sv;
    __syncthreads();
    if (d == 0) stot = red[0] + red[1] + red[2] + red[3];
    __syncthreads();
    const float s = stot;
    const float inv = 1.f / fmaxf(sqrtf(s), FEPS);
    out[(size_t)bid * 256 + d] = v * inv;
    if (d == 0) atomicAdd(&nsum[bid >> 6], s * inv * inv);
}

// final L2 over the flattened (K*D) per n
__global__ void nv_final(float* __restrict__ out, const float* __restrict__ nsum) {
    const int idx = blockIdx.x * 256 + threadIdx.x;
    const int n = idx >> 14;             // /16384
    out[idx] *= 1.f / fmaxf(sqrtf(nsum[n]), FEPS);
}

extern "C" void kernel_launch(void* const* d_in, const int* in_sizes, int n_in,
                              void* d_out, int out_size, void* d_ws, size_t ws_size,
                              hipStream_t stream)
{
    const float* x    = (const float*)d_in[0];
    const float* w    = (const float*)d_in[1];
    const float* cent = (const float*)d_in[2];
    float* out = (float*)d_out;

    // ws layout: suma[NB*K] | nsum[NB] (padded to 1KB) | wT[D*K]
    float* suma = (float*)d_ws;
    float* nsum = (float*)((char*)d_ws + (size_t)NB * K * 4);
    float* wT   = (float*)((char*)d_ws + (size_t)NB * K * 4 + 1024);

    hipMemsetAsync(d_ws, 0, (size_t)NB * K * 4 + 1024, stream);
    hipMemsetAsync(d_out, 0, (size_t)NB * K * D * sizeof(float), stream);

    nv_prep<<<(D * K) / 256, 256, 0, stream>>>(w, wT);
    dim3 g(S, NB);
    nv_main<<<g, 256, 0, stream>>>(x, wT, out, suma);
    nv_finish_row<<<NB * K, 256, 0, stream>>>(cent, suma, out, nsum);
    nv_final<<<(NB * K * D) / 256, 256, 0, stream>>>(out, nsum);
}

// Round 2
// 242.479 us; speedup vs baseline: 2.0687x; 2.0687x over previous
//
#include <hip/hip_runtime.h>

#define FEPS 1e-12f

typedef __attribute__((ext_vector_type(8))) short short8;   // 8 bf16 = 4 VGPR
typedef __attribute__((ext_vector_type(4))) float floatx4;  // MFMA C/D

constexpr int NB = 64, D = 256, T = 4096, K = 64, S = 8;
constexpr int TBLK = T / S;     // 512 pixels per block
constexpr int TC = 64;          // pixels per chunk
constexpr int NCH = TBLK / TC;  // 8 chunks

// f32 -> bf16 round-to-nearest-even
__device__ __forceinline__ unsigned short f2bf(float f) {
    unsigned u = __float_as_uint(f);
    return (unsigned short)((u + 0x7FFFu + ((u >> 16) & 1u)) >> 16);
}
__device__ __forceinline__ unsigned pk2(float a, float b) {
    return (unsigned)f2bf(a) | ((unsigned)f2bf(b) << 16);
}

// Fused: L2-norm factor + logits MFMA-GEMM + softmax + aggregation MFMA-GEMM.
// grid = (S, NB), block = 256 (4 waves). LDS ~74 KB -> 2 blocks/CU.
// K-order inside MFMA fragments: F(g,j) = 8g+j for BOTH operands of BOTH
// GEMMs (manual/manual loads -> any consistent bijection is correct).
__global__ __launch_bounds__(256, 2)
void nv_main(const float* __restrict__ x, const float* __restrict__ w,
             float* __restrict__ vlad, float* __restrict__ suma)
{
    __shared__ unsigned short xs1[TC * D];  // [t][d ^ 8*(t&31)]  GEMM1 B
    __shared__ unsigned short xs2[D * TC];  // [d][t ^ 8*(d&7)]   GEMM2 B
    __shared__ unsigned short bm[K * TC];   // [k][t ^ 8*(k&7)]   GEMM2 A
    __shared__ float sps[TC][4];            // per-wave softmax denom partials
    __shared__ float sqp[4][TC];            // per-wave sumsq partials

    const int tid = threadIdx.x;
    const int wv = tid >> 6, ln = tid & 63;
    const int m = ln & 15, g = ln >> 4;
    const int n = blockIdx.y;

    const float* xn = x + (size_t)n * D * T;

    // Resident W A-frags: wave wv owns GEMM1 m-tile = clusters [16wv,16wv+16)
    short8 wf[8];
    {
        const float* wp = w + (16 * wv + m) * D + 8 * g;
        #pragma unroll
        for (int ks = 0; ks < 8; ++ks) {
            float4 q0 = *(const float4*)(wp + 32 * ks);
            float4 q1 = *(const float4*)(wp + 32 * ks + 4);
            union { short8 v; unsigned u[4]; } t_;
            t_.u[0] = pk2(q0.x, q0.y); t_.u[1] = pk2(q0.z, q0.w);
            t_.u[2] = pk2(q1.x, q1.y); t_.u[3] = pk2(q1.z, q1.w);
            wf[ks] = t_.v;
        }
    }

    floatx4 acc[4][4];                       // GEMM2 acc [mt(k)][nt(d)]
    floatx4 fzero = {0.f, 0.f, 0.f, 0.f};
    #pragma unroll
    for (int a = 0; a < 4; ++a)
        #pragma unroll
        for (int b = 0; b < 4; ++b) acc[a][b] = fzero;
    float sa[4] = {0.f, 0.f, 0.f, 0.f};      // sum_t a for k = 16wv+4g+reg

    for (int c = 0; c < NCH; ++c) {
        const int t0 = blockIdx.x * TBLK + c * TC;
        __syncthreads();                     // xs/sqp free (prev chunk done)

        // ---- stage: global f32 -> bf16 into xs1 (via 4x4 lane-transpose) + xs2
        float4 sq4 = {0.f, 0.f, 0.f, 0.f};
        #pragma unroll
        for (int s = 0; s < 16; ++s) {
            const int d = 64 * wv + 4 * s + g;
            float4 v = *(const float4*)(xn + d * T + t0 + 4 * m);
            sq4.x = fmaf(v.x, v.x, sq4.x); sq4.y = fmaf(v.y, v.y, sq4.y);
            sq4.z = fmaf(v.z, v.z, sq4.z); sq4.w = fmaf(v.w, v.w, sq4.w);
            unsigned lo = pk2(v.x, v.y), hi = pk2(v.z, v.w);
            uint2 st2; st2.x = lo; st2.y = hi;          // 4 bf16, t-contiguous
            *(uint2*)(&xs2[d * TC + ((4 * m) ^ (8 * (d & 7)))]) = st2;
            // 4x4 bf16 transpose across lanes {m, g=0..3} (d rows <-> t cols)
            unsigned plo = __shfl_xor(lo, 16), phi = __shfl_xor(hi, 16);
            unsigned lo1, hi1;
            if ((g & 1) == 0) { lo1 = (lo & 0xFFFFu) | (plo << 16);
                                hi1 = (hi & 0xFFFFu) | (phi << 16); }
            else              { lo1 = (lo >> 16) | (plo & 0xFFFF0000u);
                                hi1 = (hi >> 16) | (phi & 0xFFFF0000u); }
            unsigned slo = __shfl_xor(lo1, 32), shi = __shfl_xor(hi1, 32);
            uint2 ot;
            if ((g & 2) == 0) { ot.x = lo1; ot.y = slo; }
            else              { ot.x = shi; ot.y = hi1; }
            const int tt = 4 * m + g;                   // t this lane now owns
            const int db = 64 * wv + 4 * s;             // 4 d's, ascending
            *(uint2*)(&xs1[tt * D + (db ^ (8 * (tt & 31)))]) = ot;
        }
        // per-t sumsq partial (this wave's 64 d's): reduce over g
        sq4.x += __shfl_xor(sq4.x, 16); sq4.y += __shfl_xor(sq4.y, 16);
        sq4.z += __shfl_xor(sq4.z, 16); sq4.w += __shfl_xor(sq4.w, 16);
        sq4.x += __shfl_xor(sq4.x, 32); sq4.y += __shfl_xor(sq4.y, 32);
        sq4.z += __shfl_xor(sq4.z, 32); sq4.w += __shfl_xor(sq4.w, 32);
        if (g == 0) *(float4*)(&sqp[wv][4 * m]) = sq4;
        __syncthreads();

        // ---- r[t] = 1/max(||x[:,t]||,eps) for this lane's 4 t-columns
        float r4[4];
        #pragma unroll
        for (int nt = 0; nt < 4; ++nt) {
            const int t = 16 * nt + m;
            float ss = sqp[0][t] + sqp[1][t] + sqp[2][t] + sqp[3][t];
            r4[nt] = 1.f / fmaxf(sqrtf(ss), FEPS);
        }

        // ---- GEMM1: z[16wv..+16 k][64 t] = W * x  (contract d=256)
        floatx4 z[4];
        #pragma unroll
        for (int nt = 0; nt < 4; ++nt) z[nt] = fzero;
        #pragma unroll
        for (int ks = 0; ks < 8; ++ks) {
            #pragma unroll
            for (int nt = 0; nt < 4; ++nt) {
                const int t = 16 * nt + m;
                short8 bfr = *(const short8*)(
                    &xs1[t * D + ((32 * ks + 8 * g) ^ (8 * (t & 31)))]);
                z[nt] = __builtin_amdgcn_mfma_f32_16x16x32_bf16(
                    wf[ks], bfr, z[nt], 0, 0, 0);
            }
        }

        // ---- softmax over k (no max-sub: |logit| <= |w_row| ~ 1)
        float e[4][4], psum[4];
        #pragma unroll
        for (int nt = 0; nt < 4; ++nt) {
            const float r = r4[nt];
            float p = 0.f;
            #pragma unroll
            for (int reg = 0; reg < 4; ++reg) {
                float ex = __expf(z[nt][reg] * r);
                e[nt][reg] = ex; p += ex;
            }
            psum[nt] = p;
        }
        #pragma unroll
        for (int nt = 0; nt < 4; ++nt) {     // reduce over g: wave's 16 k's
            psum[nt] += __shfl_xor(psum[nt], 16);
            psum[nt] += __shfl_xor(psum[nt], 32);
        }
        if (g == 0) {
            #pragma unroll
            for (int nt = 0; nt < 4; ++nt) sps[16 * nt + m][wv] = psum[nt];
        }
        __syncthreads();
        #pragma unroll
        for (int nt = 0; nt < 4; ++nt) {
            const int t = 16 * nt + m;
            float4 sv = *(const float4*)(&sps[t][0]);
            const float inv = 1.f / (sv.x + sv.y + sv.z + sv.w);
            const float br = inv * r4[nt];
            #pragma unroll
            for (int reg = 0; reg < 4; ++reg) {
                const int k = 16 * wv + 4 * g + reg;
                bm[k * TC + (t ^ (8 * (k & 7)))] = f2bf(e[nt][reg] * br);
                sa[reg] += e[nt][reg] * inv;
            }
        }
        __syncthreads();                     // bm ready for all waves

        // ---- GEMM2: acc[k][d] += b[k][t] * x[d][t]  (contract t=64)
        #pragma unroll
        for (int kt = 0; kt < 2; ++kt) {
            short8 af[4], bf[4];
            #pragma unroll
            for (int mt = 0; mt < 4; ++mt) {
                const int k = 16 * mt + m;
                af[mt] = *(const short8*)(
                    &bm[k * TC + ((32 * kt + 8 * g) ^ (8 * (k & 7)))]);
            }
            #pragma unroll
            for (int nt = 0; nt < 4; ++nt) {
                const int d = 64 * wv + 16 * nt + m;
                bf[nt] = *(const short8*)(
                    &xs2[d * TC + ((32 * kt + 8 * g) ^ (8 * (d & 7)))]);
            }
            #pragma unroll
            for (int mt = 0; mt < 4; ++mt)
                #pragma unroll
                for (int nt = 0; nt < 4; ++nt)
                    acc[mt][nt] = __builtin_amdgcn_mfma_f32_16x16x32_bf16(
                        af[mt], bf[nt], acc[mt][nt], 0, 0, 0);
        }
    }

    // ---- flush vlad partials (8 t-split blocks per n) + suma
    float* vout = vlad + (size_t)n * K * D;
    #pragma unroll
    for (int mt = 0; mt < 4; ++mt)
        #pragma unroll
        for (int nt = 0; nt < 4; ++nt)
            #pragma unroll
            for (int reg = 0; reg < 4; ++reg)
                atomicAdd(&vout[(16 * mt + 4 * g + reg) * D
                                + 64 * wv + 16 * nt + m], acc[mt][nt][reg]);
    #pragma unroll
    for (int reg = 0; reg < 4; ++reg) {
        float v = sa[reg];
        v += __shfl_xor(v, 1); v += __shfl_xor(v, 2);
        v += __shfl_xor(v, 4); v += __shfl_xor(v, 8);
        if (m == 0) atomicAdd(&suma[n * K + 16 * wv + 4 * g + reg], v);
    }
}

// per (n,k): subtract suma*centroid, intra-normalize over d, accum final sumsq
__global__ void nv_finish_row(const float* __restrict__ cent,
                              const float* __restrict__ suma,
                              float* __restrict__ out,
                              float* __restrict__ nsum)
{
    const int bid = blockIdx.x;          // n*64 + k
    const int k = bid & 63;
    const int d = threadIdx.x;
    float v = out[(size_t)bid * 256 + d] - suma[bid] * cent[k * 256 + d];
    float sv = v * v;
    #pragma unroll
    for (int msk = 1; msk < 64; msk <<= 1) sv += __shfl_xor(sv, msk);
    __shared__ float red[4];
    __shared__ float stot;
    if ((d & 63) == 0) red[d >> 6] = sv;
    __syncthreads();
    if (d == 0) stot = red[0] + red[1] + red[2] + red[3];
    __syncthreads();
    const float s = stot;
    const float inv = 1.f / fmaxf(sqrtf(s), FEPS);
    out[(size_t)bid * 256 + d] = v * inv;
    if (d == 0) atomicAdd(&nsum[bid >> 6], s * inv * inv);
}

// final L2 over the flattened (K*D) per n
__global__ void nv_final(float* __restrict__ out, const float* __restrict__ nsum) {
    const int idx = blockIdx.x * 256 + threadIdx.x;
    const int n = idx >> 14;             // /16384
    out[idx] *= 1.f / fmaxf(sqrtf(nsum[n]), FEPS);
}

extern "C" void kernel_launch(void* const* d_in, const int* in_sizes, int n_in,
                              void* d_out, int out_size, void* d_ws, size_t ws_size,
                              hipStream_t stream)
{
    const float* x    = (const float*)d_in[0];
    const float* w    = (const float*)d_in[1];
    const float* cent = (const float*)d_in[2];
    float* out = (float*)d_out;

    // ws layout: suma[NB*K] | nsum[NB] (padded region to 1KB)
    float* suma = (float*)d_ws;
    float* nsum = (float*)((char*)d_ws + (size_t)NB * K * 4);

    hipMemsetAsync(d_ws, 0, (size_t)NB * K * 4 + 1024, stream);
    hipMemsetAsync(d_out, 0, (size_t)NB * K * D * sizeof(float), stream);

    dim3 g(S, NB);
    nv_main<<<g, 256, 0, stream>>>(x, w, out, suma);
    nv_finish_row<<<NB * K, 256, 0, stream>>>(cent, suma, out, nsum);
    nv_final<<<(NB * K * D) / 256, 256, 0, stream>>>(out, nsum);
}